// Round 8
// baseline (261.445 us; speedup 1.0000x reference)
//
#include <hip/hip_runtime.h>
#include <hip/hip_bf16.h>

#define N_ 32
#define C_ 128
#define H_ 56
#define W_ 56
#define K_ 256
#define HW_ (H_*W_)
#define HP_ 58   // padded spatial dim

typedef __attribute__((ext_vector_type(8))) __bf16 bf16x8;
typedef __attribute__((ext_vector_type(8))) unsigned short ushort8;
typedef __attribute__((ext_vector_type(4))) float f32x4;

__device__ __forceinline__ unsigned short f2bf(float f) {
    unsigned int u = __builtin_bit_cast(unsigned int, f);
    u += 0x7FFFu + ((u >> 16) & 1u);   // round-to-nearest-even
    return (unsigned short)(u >> 16);
}

// ---------------- weight repack: OIHW fp32 -> fragment-major bf16 ----------
// wp2[((tap*16 + kgq)*4 + cc)*64 + lane][j]: k = kgq*16+(lane&15), c = cc*32+(lane>>4)*8+j
__global__ void repack_w2_kernel(const float* __restrict__ w,
                                 unsigned short* __restrict__ wp2) {
    int o = blockIdx.x * 256 + threadIdx.x;
    if (o >= 9 * 16 * 4 * 64 * 8) return;
    int j   = o & 7;
    int l   = (o >> 3) & 63;
    int cc  = (o >> 9) & 3;
    int kg  = (o >> 11) & 15;
    int tap = o >> 15;
    int k = kg * 16 + (l & 15);
    int c = cc * 32 + (l >> 4) * 8 + j;
    wp2[o] = f2bf(w[(k * C_ + c) * 9 + tap]);
}

// ---------------- x prepack: NCHW fp32 -> padded NHWC bf16 -----------------
// x_pad[n][hp][wp][c], hp,wp in [0,58), zero halo ring. One block per (n,hp).
__global__ void pack_x_kernel(const float* __restrict__ x,
                              unsigned short* __restrict__ xp) {
    __shared__ unsigned short Lt[128 * 57];   // [c][w], stride 57
    const int t  = threadIdx.x;               // 256
    const int b  = blockIdx.x;                // n*58 + hp
    const int n  = b / HP_;
    const int hp = b - n * HP_;
    unsigned short* orow = xp + ((size_t)(n * HP_ + hp) * HP_) * 128;

    ushort8 z = {0, 0, 0, 0, 0, 0, 0, 0};
    if (hp == 0 || hp == HP_ - 1) {
        for (int u = t; u < 928; u += 256)
            *(ushort8*)(orow + u * 8) = z;
        return;
    }
    const int h = hp - 1;
    const float* src = x + ((size_t)n * C_ * HW_ + h * W_);
    #pragma unroll
    for (int k = 0; k < 28; ++k) {
        int idx = k * 256 + t;               // 7168 = 128c x 56w
        int c = idx / 56, w2 = idx - 56 * c;
        Lt[c * 57 + w2] = f2bf(src[c * HW_ + w2]);
    }
    __syncthreads();
    for (int u = t; u < 928; u += 256) {     // 58 wp x 16 c8
        int wp = u >> 4, c8 = u & 15;
        ushort8 v = z;
        if (wp >= 1 && wp <= 56) {
            #pragma unroll
            for (int j = 0; j < 8; ++j)
                v[j] = Lt[(c8 * 8 + j) * 57 + (wp - 1)];
        }
        *(ushort8*)(orow + u * 8) = v;
    }
}

// ---------------- main conv: LDS-free streaming implicit GEMM --------------
// Wave tile 64 kout x 64 px (mi=4, ni=4, acc=64 regs -> 16 waves/CU).
// Block = 4 waves: ONE 64-kout group (kg) x 4 consecutive 64-px spans ->
// all waves share the weight stream (L1). px spans tile flattened (n,p)
// space: 1568 spans of 64 (49/image, exact). B operand read directly from
// padded-NHWC xp (per-lane dwordx4; 9-tap re-reads served by L1, window
// ~15-26 KB/block/chunk). No LDS, no barriers.
__launch_bounds__(256, 4)
__global__ void conv_mfma7_kernel(const unsigned short* __restrict__ xp,
                                  const unsigned short* __restrict__ wp2,
                                  const float* __restrict__ bias,
                                  float* __restrict__ out) {
    const int t    = threadIdx.x;
    const int lane = t & 63;
    const int wid  = t >> 6;

    // bijective XCD swizzle (1568 % 8 == 0): 196 contiguous blocks per XCD
    const int b    = blockIdx.x;
    const int orig = (b & 7) * 196 + (b >> 3);
    const int kg   = orig & 3;           // 64-kout group
    const int grp  = orig >> 2;          // [0, 392) span-quad
    const int S    = grp * 4 + wid;      // global span id [0, 1568)
    const int n    = S / 49;
    const int p0   = (S - n * 49) * 64;

    const int lp = lane & 15;
    const int lk = lane >> 4;

    // per-ni base pointers into xp (element units); tap/cc add offsets
    const unsigned short* bptr[4];
    #pragma unroll
    for (int ni = 0; ni < 4; ++ni) {
        int p = p0 + ni * 16 + lp;
        int h = p / 56;
        int w = p - 56 * h;
        bptr[ni] = xp + (((size_t)(n * HP_ + h) * HP_ + w) * 128 + lk * 8);
    }

    f32x4 acc[4][4];   // [mi][ni]
    #pragma unroll
    for (int mi = 0; mi < 4; ++mi)
        #pragma unroll
        for (int ni = 0; ni < 4; ++ni)
            acc[mi][ni] = (f32x4){0.f, 0.f, 0.f, 0.f};

    const ushort8* W8 = (const ushort8*)wp2;
    const int kgq4 = kg * 4;             // kgq = kg*4 + mi

    for (int cc = 0; cc < 4; ++cc) {
        #pragma unroll
        for (int tap = 0; tap < 9; ++tap) {
            const int r    = tap / 3;
            const int s    = tap - 3 * r;
            const int xoff = (r * HP_ + s) * 128 + cc * 32;   // element units

            bf16x8 a[4];
            #pragma unroll
            for (int mi = 0; mi < 4; ++mi)
                a[mi] = __builtin_bit_cast(bf16x8,
                    W8[tap * 4096 + ((kgq4 + mi) * 4 + cc) * 64 + lane]);

            bf16x8 bb[4];
            #pragma unroll
            for (int ni = 0; ni < 4; ++ni)
                bb[ni] = __builtin_bit_cast(bf16x8,
                    *(const ushort8*)(bptr[ni] + xoff));

            #pragma unroll
            for (int ni = 0; ni < 4; ++ni)
                #pragma unroll
                for (int mi = 0; mi < 4; ++mi)
                    acc[mi][ni] = __builtin_amdgcn_mfma_f32_16x16x32_bf16(
                        a[mi], bb[ni], acc[mi][ni], 0, 0, 0);
        }
    }

    // epilogue: bias + fp32 store (out is NCHW, px flat -> contiguous stores)
    #pragma unroll
    for (int mi = 0; mi < 4; ++mi) {
        const int kbase = kg * 64 + mi * 16 + lk * 4;
        f32x4 bv = *(const f32x4*)(bias + kbase);
        #pragma unroll
        for (int j = 0; j < 4; ++j) {
            float* op = out + ((size_t)(n * K_ + kbase + j) * HW_);
            #pragma unroll
            for (int ni = 0; ni < 4; ++ni)
                op[p0 + ni * 16 + lp] = acc[mi][ni][j] + bv[j];
        }
    }
}

// ---------------- fallback (reg-staged fp32 path, no xp needed) ------------
__launch_bounds__(256, 2)
__global__ void conv_mfma3_kernel(const float* __restrict__ x,
                                  const unsigned short* __restrict__ wp2,
                                  const float* __restrict__ bias,
                                  float* __restrict__ out) {
    __shared__ unsigned short Xt[2][232 * 40];
    const int t    = threadIdx.x;
    const int lane = t & 63;
    const int wid  = t >> 6;
    const int b    = blockIdx.x;
    const int orig = (b & 7) * 112 + (b >> 3);
    const int n    = orig / 28;
    const int rp   = orig - n * 28;
    const int h0   = rp * 2;
    const int lp = lane & 15;
    const int lk = lane >> 4;
    int bofs[7];
    #pragma unroll
    for (int ni = 0; ni < 7; ++ni) {
        int p  = ni * 16 + lp;
        int hr = (p >= 56) ? 1 : 0;
        int pw = p - hr * 56;
        bofs[ni] = (hr * 58 + pw) * 40 + lk * 8;
    }
    bool  ok[4], v928[4];
    const float* xq[4];
    int   ldsw[4];
    #pragma unroll
    for (int i = 0; i < 4; ++i) {
        int it = i * 256 + t;
        v928[i] = (it < 928);
        int itc  = v928[i] ? it : 0;
        int csub = (itc >= 232) + (itc >= 464) + (itc >= 696);
        int col  = itc - 232 * csub;
        int hh   = col / 58;
        int ww   = col - 58 * hh;
        int hin  = h0 + hh - 1;
        int win  = ww - 1;
        ok[i]   = v928[i] && (unsigned)hin < 56u && (unsigned)win < 56u;
        xq[i]   = x + (((n * C_ + csub * 8) * H_ + hin) * W_ + win);
        ldsw[i] = col * 40 + csub * 8;
    }
    float xv[4][8];
#define STAGE_LOAD(CH)                                                 \
    _Pragma("unroll")                                                  \
    for (int i = 0; i < 4; ++i)                                        \
        _Pragma("unroll")                                              \
        for (int j = 0; j < 8; ++j)                                    \
            xv[i][j] = ok[i] ? xq[i][((CH) * 32 + j) * HW_] : 0.f;
#define STAGE_WRITE(BUF)                                               \
    _Pragma("unroll")                                                  \
    for (int i = 0; i < 4; ++i)                                        \
        if (v928[i]) {                                                 \
            ushort8 v;                                                 \
            _Pragma("unroll")                                          \
            for (int j = 0; j < 8; ++j) v[j] = f2bf(xv[i][j]);         \
            *(ushort8*)(&Xt[BUF][ldsw[i]]) = v;                        \
        }
    f32x4 acc[4][7];
    #pragma unroll
    for (int mi = 0; mi < 4; ++mi)
        #pragma unroll
        for (int ni = 0; ni < 7; ++ni)
            acc[mi][ni] = (f32x4){0.f, 0.f, 0.f, 0.f};
    STAGE_LOAD(0)
    STAGE_WRITE(0)
    __syncthreads();
    const ushort8* W8 = (const ushort8*)wp2;
    for (int cc = 0; cc < 4; ++cc) {
        const int cur = cc & 1;
        if (cc < 3) { STAGE_LOAD(cc + 1) }
        const int tb = wid * 1024 + cc * 64 + lane;
        #pragma unroll
        for (int tap = 0; tap < 9; ++tap) {
            const int r    = tap / 3;
            const int s    = tap - 3 * r;
            const int toff = (r * 58 + s) * 40;
            bf16x8 a[4];
            #pragma unroll
            for (int mi = 0; mi < 4; ++mi)
                a[mi] = __builtin_bit_cast(bf16x8, W8[tap * 4096 + tb + mi * 256]);
            bf16x8 bfr[7];
            #pragma unroll
            for (int ni = 0; ni < 7; ++ni)
                bfr[ni] = __builtin_bit_cast(bf16x8,
                    *(const ushort8*)(&Xt[cur][bofs[ni] + toff]));
            #pragma unroll
            for (int ni = 0; ni < 7; ++ni)
                #pragma unroll
                for (int mi = 0; mi < 4; ++mi)
                    acc[mi][ni] = __builtin_amdgcn_mfma_f32_16x16x32_bf16(
                        a[mi], bfr[ni], acc[mi][ni], 0, 0, 0);
        }
        if (cc < 3) {
            STAGE_WRITE(cur ^ 1)
            __syncthreads();
        }
    }
    #pragma unroll
    for (int mi = 0; mi < 4; ++mi) {
        #pragma unroll
        for (int j = 0; j < 4; ++j) {
            int kout = wid * 64 + mi * 16 + lk * 4 + j;
            float bv = bias[kout];
            float* op = out + ((n * K_ + kout) * H_ + h0) * W_;
            #pragma unroll
            for (int ni = 0; ni < 7; ++ni) {
                int p  = ni * 16 + lp;
                int hr = (p >= 56) ? 1 : 0;
                int pw = p - hr * 56;
                op[hr * W_ + pw] = acc[mi][ni][j] + bv;
            }
        }
    }
#undef STAGE_LOAD
#undef STAGE_WRITE
}

__global__ void conv_naive_kernel(const float* __restrict__ x,
                                  const float* __restrict__ w,
                                  const float* __restrict__ b,
                                  float* __restrict__ out) {
    int idx = blockIdx.x * 256 + threadIdx.x;
    if (idx >= N_ * K_ * HW_) return;
    int pw = idx % 56; int tmp = idx / 56;
    int h  = tmp % 56; tmp /= 56;
    int k  = tmp % 256; int n = tmp / 256;
    float acc = b[k];
    for (int c = 0; c < C_; ++c)
        for (int r = 0; r < 3; ++r) {
            int hin = h + r - 1;
            if ((unsigned)hin >= 56u) continue;
            for (int s = 0; s < 3; ++s) {
                int win = pw + s - 1;
                if ((unsigned)win >= 56u) continue;
                acc += x[((n * C_ + c) * H_ + hin) * W_ + win] * w[(k * C_ + c) * 9 + r * 3 + s];
            }
        }
    out[idx] = acc;
}

extern "C" void kernel_launch(void* const* d_in, const int* in_sizes, int n_in,
                              void* d_out, int out_size, void* d_ws, size_t ws_size,
                              hipStream_t stream) {
    const float* x = (const float*)d_in[0];
    const float* w = (const float*)d_in[1];
    const float* b = (const float*)d_in[2];
    float* out = (float*)d_out;

    const size_t xp_bytes = (size_t)N_ * HP_ * HP_ * C_ * 2;              // 27,557,888
    const size_t wp_bytes = (size_t)9 * 16 * 4 * 64 * 8 * 2;              // 589,824

    if (ws_size >= xp_bytes + wp_bytes) {
        unsigned short* xpad = (unsigned short*)d_ws;
        unsigned short* wp2  = (unsigned short*)((char*)d_ws + xp_bytes);
        pack_x_kernel<<<N_ * HP_, 256, 0, stream>>>(x, xpad);
        repack_w2_kernel<<<(9 * 16 * 4 * 64 * 8 + 255) / 256, 256, 0, stream>>>(w, wp2);
        conv_mfma7_kernel<<<1568, 256, 0, stream>>>(xpad, wp2, b, out);
    } else if (ws_size >= wp_bytes) {
        unsigned short* wp2 = (unsigned short*)d_ws;
        repack_w2_kernel<<<(9 * 16 * 4 * 64 * 8 + 255) / 256, 256, 0, stream>>>(w, wp2);
        conv_mfma3_kernel<<<896, 256, 0, stream>>>(x, wp2, b, out);
    } else {
        conv_naive_kernel<<<(N_ * K_ * HW_ + 255) / 256, 256, 0, stream>>>(x, w, b, out);
    }
}

// Round 9
// 103.961 us; speedup vs baseline: 2.5148x; 2.5148x over previous
//
#include <hip/hip_runtime.h>
#include <hip/hip_bf16.h>

#define N_ 32
#define C_ 128
#define H_ 56
#define W_ 56
#define K_ 256
#define HW_ (H_*W_)
#define HP_ 58   // padded spatial dim
#define STEPS 18 // 9 taps x 2 channel-halves (BK=64)

typedef __attribute__((ext_vector_type(8))) __bf16 bf16x8;
typedef __attribute__((ext_vector_type(8))) unsigned short ushort8;
typedef __attribute__((ext_vector_type(4))) float f32x4;

typedef __attribute__((address_space(1))) const unsigned int g1_u32;
typedef __attribute__((address_space(3))) unsigned int l3_u32;

__device__ __forceinline__ void dma16(const void* g, void* l) {
    __builtin_amdgcn_global_load_lds((g1_u32*)g, (l3_u32*)l, 16, 0, 0);
}

__device__ __forceinline__ unsigned short f2bf(float f) {
    unsigned int u = __builtin_bit_cast(unsigned int, f);
    u += 0x7FFFu + ((u >> 16) & 1u);   // round-to-nearest-even
    return (unsigned short)(u >> 16);
}

// ---------------- weight repack: OIHW fp32 -> A-tile-major bf16 ------------
// wp3[tap][hf][cc2][kg][lane][j] : k = kg*16+(lane&15), c = hf*64+cc2*32+(lane>>4)*8+j
// => each (tap,hf) slice is a contiguous 32KB A-tile, DMA-able linearly;
//    A-fragment reads are ds_read_b128 at consecutive lanes (conflict-free).
__global__ void repack_w3_kernel(const float* __restrict__ w,
                                 unsigned short* __restrict__ wp3) {
    int o = blockIdx.x * 256 + threadIdx.x;
    if (o >= 9 * 2 * 2 * 16 * 64 * 8) return;
    int j   = o & 7;
    int l   = (o >> 3) & 63;
    int kg  = (o >> 9) & 15;
    int cc2 = (o >> 13) & 1;
    int hf  = (o >> 14) & 1;
    int tap = o >> 15;
    int k = kg * 16 + (l & 15);
    int c = hf * 64 + cc2 * 32 + (l >> 4) * 8 + j;
    wp3[o] = f2bf(w[(k * C_ + c) * 9 + tap]);
}

// ---------------- x prepack: NCHW fp32 -> padded NHWC bf16 -----------------
// x_pad[n][hp][wp][c], hp,wp in [0,58), zero halo ring. One block per (n,hp).
__global__ void pack_x_kernel(const float* __restrict__ x,
                              unsigned short* __restrict__ xp) {
    __shared__ unsigned short Lt[128 * 57];   // [c][w], stride 57
    const int t  = threadIdx.x;               // 256
    const int b  = blockIdx.x;                // n*58 + hp
    const int n  = b / HP_;
    const int hp = b - n * HP_;
    unsigned short* orow = xp + ((size_t)(n * HP_ + hp) * HP_) * 128;

    ushort8 z = {0, 0, 0, 0, 0, 0, 0, 0};
    if (hp == 0 || hp == HP_ - 1) {
        for (int u = t; u < 928; u += 256)
            *(ushort8*)(orow + u * 8) = z;
        return;
    }
    const int h = hp - 1;
    const float* src = x + ((size_t)n * C_ * HW_ + h * W_);
    #pragma unroll
    for (int k = 0; k < 28; ++k) {
        int idx = k * 256 + t;               // 7168 = 128c x 56w
        int c = idx / 56, w2 = idx - 56 * c;
        Lt[c * 57 + w2] = f2bf(src[c * HW_ + w2]);
    }
    __syncthreads();
    for (int u = t; u < 928; u += 256) {     // 58 wp x 16 c8
        int wp = u >> 4, c8 = u & 15;
        ushort8 v = z;
        if (wp >= 1 && wp <= 56) {
            #pragma unroll
            for (int j = 0; j < 8; ++j)
                v[j] = Lt[(c8 * 8 + j) * 57 + (wp - 1)];
        }
        *(ushort8*)(orow + u * 8) = v;
    }
}

// ---------------- main conv: 256x128 implicit GEMM, both operands in LDS ---
// Grid 784 N-tiles (128 px each, flat over n,h,w). 512 thr / 8 waves (4M x 2N),
// wave tile 64 kout x 64 px (mi=4, ni=4). K = 18 steps of 64 (tap, ch-half).
// LDS/buf: A 32KB (fragment-major) + B 16KB ([px][slot^=(px&7)]) = 48KB, dbuf.
// Per step: issue 6 DMAs (k+1) -> 8 ds_read_b128 + 32 MFMA -> vmcnt(0)+barrier.
__launch_bounds__(512, 1)
__global__ void conv_mfma8_kernel(const unsigned short* __restrict__ xp,
                                  const unsigned short* __restrict__ wp3,
                                  const float* __restrict__ bias,
                                  float* __restrict__ out) {
    __shared__ __align__(16) unsigned char Lds[2][49152];   // 96 KB

    const int t    = threadIdx.x;
    const int lane = t & 63;
    const int wid  = t >> 6;
    const int wr   = wid >> 1;    // M wave 0..3
    const int wc   = wid & 1;     // N wave 0..1
    const int lp   = lane & 15;
    const int lk   = lane >> 4;

    // bijective XCD swizzle (784 % 8 == 0): 98 contiguous N-tiles per XCD
    const int b    = blockIdx.x;
    const int orig = (b & 7) * 98 + (b >> 3);
    const int pix0 = orig * 128;

    // ---- B staging sources (2 per thread; step adds (r*58+s)*128 + hf*64) ----
    const unsigned short* bsrc[2];
    #pragma unroll
    for (int p = 0; p < 2; ++p) {
        int u   = p * 512 + t;            // 0..1023 : dest 16B-unit
        int pxd = u >> 3;
        int sl  = (u & 7) ^ (pxd & 7);    // logical slot (inverse-swizzled source)
        int px  = pix0 + pxd;
        int n   = px / HW_;
        int pr  = px - n * HW_;
        int h   = pr / W_, w = pr - W_ * h;
        bsrc[p] = xp + (((size_t)(n * HP_) + h) * HP_ + w) * 128 + sl * 8;
    }

    // ---- LDS read byte offsets (buffer-relative, step-invariant) ----
    int aoff[2][4];   // [cc2][mi]
    #pragma unroll
    for (int c2 = 0; c2 < 2; ++c2)
        #pragma unroll
        for (int mi = 0; mi < 4; ++mi)
            aoff[c2][mi] = (c2 * 1024 + (wr * 4 + mi) * 64 + lane) * 16;
    int boff[2][4];   // [cc2][ni]
    #pragma unroll
    for (int c2 = 0; c2 < 2; ++c2)
        #pragma unroll
        for (int ni = 0; ni < 4; ++ni) {
            int pxl = wc * 64 + ni * 16 + lp;
            int sl  = (c2 * 4 + lk) ^ (pxl & 7);
            boff[c2][ni] = 32768 + pxl * 128 + sl * 16;
        }

    f32x4 acc[4][4];
    #pragma unroll
    for (int mi = 0; mi < 4; ++mi)
        #pragma unroll
        for (int ni = 0; ni < 4; ++ni)
            acc[mi][ni] = (f32x4){0.f, 0.f, 0.f, 0.f};

#define STAGE(K, BUF)                                                        \
    {                                                                        \
        const int tap_ = (K) >> 1, hf_ = (K) & 1;                            \
        const unsigned short* as_ = wp3 + (tap_ * 2 + hf_) * 16384;          \
        _Pragma("unroll")                                                    \
        for (int p = 0; p < 4; ++p)                                          \
            dma16(as_ + (p * 512 + t) * 8, Lds[BUF] + (p * 512 + t) * 16);   \
        const int xo_ = ((tap_ / 3) * HP_ + (tap_ % 3)) * 128 + hf_ * 64;    \
        _Pragma("unroll")                                                    \
        for (int p = 0; p < 2; ++p)                                          \
            dma16(bsrc[p] + xo_, Lds[BUF] + 32768 + (p * 512 + t) * 16);     \
    }

    // prologue: stage step 0 into buf 0
    STAGE(0, 0)
    asm volatile("s_waitcnt vmcnt(0)" ::: "memory");
    __builtin_amdgcn_s_barrier();

    for (int k = 0; k < STEPS; ++k) {
        const int cur = k & 1;

        if (k < STEPS - 1) { STAGE(k + 1, cur ^ 1) }   // ~1200cy in flight

        const unsigned char* Lb = Lds[cur];
        #pragma unroll
        for (int c2 = 0; c2 < 2; ++c2) {
            bf16x8 a[4], bb[4];
            #pragma unroll
            for (int mi = 0; mi < 4; ++mi)
                a[mi] = __builtin_bit_cast(bf16x8, *(const ushort8*)(Lb + aoff[c2][mi]));
            #pragma unroll
            for (int ni = 0; ni < 4; ++ni)
                bb[ni] = __builtin_bit_cast(bf16x8, *(const ushort8*)(Lb + boff[c2][ni]));

            __builtin_amdgcn_s_setprio(1);
            #pragma unroll
            for (int ni = 0; ni < 4; ++ni)
                #pragma unroll
                for (int mi = 0; mi < 4; ++mi)
                    acc[mi][ni] = __builtin_amdgcn_mfma_f32_16x16x32_bf16(
                        a[mi], bb[ni], acc[mi][ni], 0, 0, 0);
            __builtin_amdgcn_s_setprio(0);
        }

        if (k < STEPS - 1) {
            asm volatile("s_waitcnt vmcnt(0)" ::: "memory");
            __builtin_amdgcn_s_barrier();
        }
    }
#undef STAGE

    // ---- epilogue: bias + fp32 store (lanes lp = consecutive px: coalesced) ----
    #pragma unroll
    for (int ni = 0; ni < 4; ++ni) {
        int px = pix0 + wc * 64 + ni * 16 + lp;
        int n  = px / HW_;
        int pr = px - n * HW_;
        float* ob = out + (size_t)n * K_ * HW_ + pr;
        #pragma unroll
        for (int mi = 0; mi < 4; ++mi) {
            int kb = wr * 64 + mi * 16 + lk * 4;
            f32x4 bv = *(const f32x4*)(bias + kb);
            #pragma unroll
            for (int j = 0; j < 4; ++j)
                ob[(size_t)(kb + j) * HW_] = acc[mi][ni][j] + bv[j];
        }
    }
}

// ---------------- fallback (reg-staged fp32 path, no workspace xp) ---------
__launch_bounds__(256, 2)
__global__ void conv_mfma3_kernel(const float* __restrict__ x,
                                  const unsigned short* __restrict__ wp2,
                                  const float* __restrict__ bias,
                                  float* __restrict__ out) {
    __shared__ unsigned short Xt[2][232 * 40];
    const int t    = threadIdx.x;
    const int lane = t & 63;
    const int wid  = t >> 6;
    const int b    = blockIdx.x;
    const int orig = (b & 7) * 112 + (b >> 3);
    const int n    = orig / 28;
    const int rp   = orig - n * 28;
    const int h0   = rp * 2;
    const int lp = lane & 15;
    const int lk = lane >> 4;
    int bofs[7];
    #pragma unroll
    for (int ni = 0; ni < 7; ++ni) {
        int p  = ni * 16 + lp;
        int hr = (p >= 56) ? 1 : 0;
        int pw = p - hr * 56;
        bofs[ni] = (hr * 58 + pw) * 40 + lk * 8;
    }
    bool  ok[4], v928[4];
    const float* xq[4];
    int   ldsw[4];
    #pragma unroll
    for (int i = 0; i < 4; ++i) {
        int it = i * 256 + t;
        v928[i] = (it < 928);
        int itc  = v928[i] ? it : 0;
        int csub = (itc >= 232) + (itc >= 464) + (itc >= 696);
        int col  = itc - 232 * csub;
        int hh   = col / 58;
        int ww   = col - 58 * hh;
        int hin  = h0 + hh - 1;
        int win  = ww - 1;
        ok[i]   = v928[i] && (unsigned)hin < 56u && (unsigned)win < 56u;
        xq[i]   = x + (((n * C_ + csub * 8) * H_ + hin) * W_ + win);
        ldsw[i] = col * 40 + csub * 8;
    }
    float xv[4][8];
#define STAGE_LOAD(CH)                                                 \
    _Pragma("unroll")                                                  \
    for (int i = 0; i < 4; ++i)                                        \
        _Pragma("unroll")                                              \
        for (int j = 0; j < 8; ++j)                                    \
            xv[i][j] = ok[i] ? xq[i][((CH) * 32 + j) * HW_] : 0.f;
#define STAGE_WRITE(BUF)                                               \
    _Pragma("unroll")                                                  \
    for (int i = 0; i < 4; ++i)                                        \
        if (v928[i]) {                                                 \
            ushort8 v;                                                 \
            _Pragma("unroll")                                          \
            for (int j = 0; j < 8; ++j) v[j] = f2bf(xv[i][j]);         \
            *(ushort8*)(&Xt[BUF][ldsw[i]]) = v;                        \
        }
    f32x4 acc[4][7];
    #pragma unroll
    for (int mi = 0; mi < 4; ++mi)
        #pragma unroll
        for (int ni = 0; ni < 7; ++ni)
            acc[mi][ni] = (f32x4){0.f, 0.f, 0.f, 0.f};
    STAGE_LOAD(0)
    STAGE_WRITE(0)
    __syncthreads();
    const ushort8* W8 = (const ushort8*)wp2;
    for (int cc = 0; cc < 4; ++cc) {
        const int cur = cc & 1;
        if (cc < 3) { STAGE_LOAD(cc + 1) }
        const int tb = wid * 1024 + cc * 64 + lane;
        #pragma unroll
        for (int tap = 0; tap < 9; ++tap) {
            const int r    = tap / 3;
            const int s    = tap - 3 * r;
            const int toff = (r * 58 + s) * 40;
            bf16x8 a[4];
            #pragma unroll
            for (int mi = 0; mi < 4; ++mi)
                a[mi] = __builtin_bit_cast(bf16x8, W8[tap * 4096 + tb + mi * 256]);
            bf16x8 bfr[7];
            #pragma unroll
            for (int ni = 0; ni < 7; ++ni)
                bfr[ni] = __builtin_bit_cast(bf16x8,
                    *(const ushort8*)(&Xt[cur][bofs[ni] + toff]));
            #pragma unroll
            for (int ni = 0; ni < 7; ++ni)
                #pragma unroll
                for (int mi = 0; mi < 4; ++mi)
                    acc[mi][ni] = __builtin_amdgcn_mfma_f32_16x16x32_bf16(
                        a[mi], bfr[ni], acc[mi][ni], 0, 0, 0);
        }
        if (cc < 3) {
            STAGE_WRITE(cur ^ 1)
            __syncthreads();
        }
    }
    #pragma unroll
    for (int mi = 0; mi < 4; ++mi) {
        #pragma unroll
        for (int j = 0; j < 4; ++j) {
            int kout = wid * 64 + mi * 16 + lk * 4 + j;
            float bv = bias[kout];
            float* op = out + ((n * K_ + kout) * H_ + h0) * W_;
            #pragma unroll
            for (int ni = 0; ni < 7; ++ni) {
                int p  = ni * 16 + lp;
                int hr = (p >= 56) ? 1 : 0;
                int pw = p - hr * 56;
                op[hr * W_ + pw] = acc[mi][ni][j] + bv;
            }
        }
    }
#undef STAGE_LOAD
#undef STAGE_WRITE
}

// legacy repack for the fallback path
__global__ void repack_w2_kernel(const float* __restrict__ w,
                                 unsigned short* __restrict__ wp2) {
    int o = blockIdx.x * 256 + threadIdx.x;
    if (o >= 9 * 16 * 4 * 64 * 8) return;
    int j   = o & 7;
    int l   = (o >> 3) & 63;
    int cc  = (o >> 9) & 3;
    int kg  = (o >> 11) & 15;
    int tap = o >> 15;
    int k = kg * 16 + (l & 15);
    int c = cc * 32 + (l >> 4) * 8 + j;
    wp2[o] = f2bf(w[(k * C_ + c) * 9 + tap]);
}

__global__ void conv_naive_kernel(const float* __restrict__ x,
                                  const float* __restrict__ w,
                                  const float* __restrict__ b,
                                  float* __restrict__ out) {
    int idx = blockIdx.x * 256 + threadIdx.x;
    if (idx >= N_ * K_ * HW_) return;
    int pw = idx % 56; int tmp = idx / 56;
    int h  = tmp % 56; tmp /= 56;
    int k  = tmp % 256; int n = tmp / 256;
    float acc = b[k];
    for (int c = 0; c < C_; ++c)
        for (int r = 0; r < 3; ++r) {
            int hin = h + r - 1;
            if ((unsigned)hin >= 56u) continue;
            for (int s = 0; s < 3; ++s) {
                int win = pw + s - 1;
                if ((unsigned)win >= 56u) continue;
                acc += x[((n * C_ + c) * H_ + hin) * W_ + win] * w[(k * C_ + c) * 9 + r * 3 + s];
            }
        }
    out[idx] = acc;
}

extern "C" void kernel_launch(void* const* d_in, const int* in_sizes, int n_in,
                              void* d_out, int out_size, void* d_ws, size_t ws_size,
                              hipStream_t stream) {
    const float* x = (const float*)d_in[0];
    const float* w = (const float*)d_in[1];
    const float* b = (const float*)d_in[2];
    float* out = (float*)d_out;

    const size_t xp_bytes = (size_t)N_ * HP_ * HP_ * C_ * 2;              // 27,557,888
    const size_t wp_bytes = (size_t)9 * 2 * 2 * 16 * 64 * 8 * 2;          // 589,824

    if (ws_size >= xp_bytes + wp_bytes) {
        unsigned short* xpad = (unsigned short*)d_ws;
        unsigned short* wp3  = (unsigned short*)((char*)d_ws + xp_bytes);
        pack_x_kernel<<<N_ * HP_, 256, 0, stream>>>(x, xpad);
        repack_w3_kernel<<<(9 * 2 * 2 * 16 * 64 * 8 + 255) / 256, 256, 0, stream>>>(w, wp3);
        conv_mfma8_kernel<<<784, 512, 0, stream>>>(xpad, wp3, b, out);
    } else if (ws_size >= wp_bytes) {
        unsigned short* wp2 = (unsigned short*)d_ws;
        repack_w2_kernel<<<(9 * 16 * 4 * 64 * 8 + 255) / 256, 256, 0, stream>>>(w, wp2);
        conv_mfma3_kernel<<<896, 256, 0, stream>>>(x, wp2, b, out);
    } else {
        conv_naive_kernel<<<(N_ * K_ * HW_ + 255) / 256, 256, 0, stream>>>(x, w, b, out);
    }
}

// Round 10
// 99.365 us; speedup vs baseline: 2.6312x; 1.0463x over previous
//
#include <hip/hip_runtime.h>
#include <hip/hip_bf16.h>

#define N_ 32
#define C_ 128
#define H_ 56
#define W_ 56
#define K_ 256
#define HW_ (H_*W_)
#define HP_ 58    // padded spatial dim
#define STEPS 18  // 9 taps x 2 channel-halves (BK=64)

typedef __attribute__((ext_vector_type(8))) __bf16 bf16x8;
typedef __attribute__((ext_vector_type(8))) unsigned short ushort8;
typedef __attribute__((ext_vector_type(4))) float f32x4;

typedef __attribute__((address_space(1))) const unsigned int g1_u32;
typedef __attribute__((address_space(3))) unsigned int l3_u32;

__device__ __forceinline__ void dma16(const void* g, void* l) {
    __builtin_amdgcn_global_load_lds((g1_u32*)g, (l3_u32*)l, 16, 0, 0);
}

__device__ __forceinline__ unsigned short f2bf(float f) {
    unsigned int u = __builtin_bit_cast(unsigned int, f);
    u += 0x7FFFu + ((u >> 16) & 1u);   // round-to-nearest-even
    return (unsigned short)(u >> 16);
}

// ---------------- weight repack: OIHW fp32 -> quarter-tile bf16 ------------
// wp4 layout (elements): [(step*2+rh)*8192 + ((kk*8+mi8)*64 + lane)*8 + j]
//   step = tap*2+hf ; k_out = rh*128 + mi8*16 + (lane&15)
//   c = hf*64 + kk*32 + (lane>>4)*8 + j
// Each (step,rh) slice = 16 KB, DMA'd linearly; A-frag reads are
// ds_read_b128 at 64 consecutive lanes (conflict-free).
__global__ void repack_w4_kernel(const float* __restrict__ w,
                                 unsigned short* __restrict__ wp4) {
    int o = blockIdx.x * 256 + threadIdx.x;
    if (o >= STEPS * 2 * 8192) return;
    int j    = o & 7;
    int lane = (o >> 3) & 63;
    int mi8  = (o >> 9) & 7;
    int kk   = (o >> 12) & 1;
    int rh   = (o >> 13) & 1;
    int hf   = (o >> 14) & 1;
    int tap  = o >> 15;
    int k = rh * 128 + mi8 * 16 + (lane & 15);
    int c = hf * 64 + kk * 32 + (lane >> 4) * 8 + j;
    wp4[o] = f2bf(w[(k * C_ + c) * 9 + tap]);
}

// ---------------- x prepack: NCHW fp32 -> padded NHWC bf16 -----------------
__global__ void pack_x_kernel(const float* __restrict__ x,
                              unsigned short* __restrict__ xp) {
    __shared__ unsigned short Lt[128 * 57];
    const int t  = threadIdx.x;               // 256
    const int b  = blockIdx.x;                // n*58 + hp
    const int n  = b / HP_;
    const int hp = b - n * HP_;
    unsigned short* orow = xp + ((size_t)(n * HP_ + hp) * HP_) * 128;

    ushort8 z = {0, 0, 0, 0, 0, 0, 0, 0};
    if (hp == 0 || hp == HP_ - 1) {
        for (int u = t; u < 928; u += 256)
            *(ushort8*)(orow + u * 8) = z;
        return;
    }
    const int h = hp - 1;
    const float* src = x + ((size_t)n * C_ * HW_ + h * W_);
    #pragma unroll
    for (int k = 0; k < 28; ++k) {
        int idx = k * 256 + t;
        int c = idx / 56, w2 = idx - 56 * c;
        Lt[c * 57 + w2] = f2bf(src[c * HW_ + w2]);
    }
    __syncthreads();
    for (int u = t; u < 928; u += 256) {
        int wp = u >> 4, c8 = u & 15;
        ushort8 v = z;
        if (wp >= 1 && wp <= 56) {
            #pragma unroll
            for (int j = 0; j < 8; ++j)
                v[j] = Lt[(c8 * 8 + j) * 57 + (wp - 1)];
        }
        *(ushort8*)(orow + u * 8) = v;
    }
}

// ---------------- main conv: m201-style ring pipeline ----------------------
// 256 kout x 256 px per block (392 blocks). 8 waves 2M x 4N, wave 128x64,
// BK=64 over 18 steps. LDS: ring of 8 x 16KB quarter-slots (128 KB).
// Quarter g=4k+j, j in {A0,A1,B0,B1}; slot = g&7. Per step: vmcnt(6) ->
// barrier -> 24 ds_reads -> stage B1(k+1) -> lgkmcnt(0)+barrier ->
// setprio { 64 MFMA interleaved with stages A0/A1/B0(k+2) }.
__launch_bounds__(512, 1)
__global__ void conv_mfma9_kernel(const unsigned short* __restrict__ xp,
                                  const unsigned short* __restrict__ wp4,
                                  const float* __restrict__ bias,
                                  float* __restrict__ out) {
    __shared__ __align__(16) unsigned char Lds[8][16384];

    const int t    = threadIdx.x;
    const int lane = t & 63;
    const int wid  = t >> 6;
    const int wr   = wid >> 2;   // M half 0..1
    const int wc   = wid & 3;    // N wave 0..3
    const int ph   = wc >> 1;    // B px-half this wave reads
    const int lp   = lane & 15;
    const int lk   = lane >> 4;

    // bijective XCD swizzle (392 % 8 == 0): 49 contiguous blocks per XCD
    const int b    = blockIdx.x;
    const int orig = (b & 7) * 49 + (b >> 3);
    const int pix0 = orig * 256;

    // ---- B staging sources: quarter (ph2, i) -> per-thread global ptr ----
    const unsigned short* bsrcQ[2][2];
    #pragma unroll
    for (int p2 = 0; p2 < 2; ++p2)
        #pragma unroll
        for (int i = 0; i < 2; ++i) {
            int u   = i * 512 + t;            // dest 16B-unit within quarter
            int pxd = u >> 3;
            int sl  = (u & 7) ^ (pxd & 7);    // inverse-swizzled source slot
            int px  = pix0 + p2 * 128 + pxd;
            int n   = px / HW_;
            int pr  = px - n * HW_;
            int h   = pr / W_, w = pr - W_ * h;
            bsrcQ[p2][i] = xp + (((size_t)(n * HP_) + h) * HP_ + w) * 128 + sl * 8;
        }

    // ---- LDS read byte offsets (slot-relative, step-invariant) ----
    int aoff[2][8];
    #pragma unroll
    for (int kk = 0; kk < 2; ++kk)
        #pragma unroll
        for (int mi = 0; mi < 8; ++mi)
            aoff[kk][mi] = ((kk * 8 + mi) * 64 + lane) * 16;
    int boff[2][4];
    #pragma unroll
    for (int kk = 0; kk < 2; ++kk)
        #pragma unroll
        for (int ni = 0; ni < 4; ++ni) {
            int pxd = (wc * 64 + ni * 16 + lp) & 127;
            boff[kk][ni] = (pxd * 8 + ((kk * 4 + lk) ^ (pxd & 7))) * 16;
        }

    f32x4 acc[8][4];
    #pragma unroll
    for (int mi = 0; mi < 8; ++mi)
        #pragma unroll
        for (int ni = 0; ni < 4; ++ni)
            acc[mi][ni] = (f32x4){0.f, 0.f, 0.f, 0.f};

    // stage quarter helpers (2 dma each, wave-linear dest)
#define STAGE_A(S, RH, SLOT)                                                  \
    {                                                                         \
        const unsigned short* as_ = wp4 + ((S) * 2 + (RH)) * 8192;            \
        dma16(as_ + t * 8,         Lds[SLOT] + t * 16);                       \
        dma16(as_ + (512 + t) * 8, Lds[SLOT] + (512 + t) * 16);               \
    }
#define STAGE_B(S, P2, SLOT)                                                  \
    {                                                                         \
        const int tap_ = (S) >> 1, hf_ = (S) & 1;                             \
        const int xo_  = ((tap_ / 3) * HP_ + (tap_ % 3)) * 128 + hf_ * 64;    \
        dma16(bsrcQ[P2][0] + xo_, Lds[SLOT] + t * 16);                        \
        dma16(bsrcQ[P2][1] + xo_, Lds[SLOT] + (512 + t) * 16);                \
    }

    // prologue: quarters 0..6 in issue order
    STAGE_A(0, 0, 0) STAGE_A(0, 1, 1) STAGE_B(0, 0, 2) STAGE_B(0, 1, 3)
    STAGE_A(1, 0, 4) STAGE_A(1, 1, 5) STAGE_B(1, 0, 6)

    #pragma unroll
    for (int k = 0; k < STEPS; ++k) {
        if (k < STEPS - 1) asm volatile("s_waitcnt vmcnt(6)" ::: "memory");
        else               asm volatile("s_waitcnt vmcnt(0)" ::: "memory");
        __builtin_amdgcn_s_barrier();

        // ---- phase 0: all ds_reads for this step ----
        const unsigned char* As = Lds[(4 * k + wr) & 7];
        const unsigned char* Bs = Lds[(4 * k + 2 + ph) & 7];
        bf16x8 a[2][8], bb[2][4];
        #pragma unroll
        for (int kk = 0; kk < 2; ++kk) {
            #pragma unroll
            for (int mi = 0; mi < 8; ++mi)
                a[kk][mi] = __builtin_bit_cast(bf16x8, *(const ushort8*)(As + aoff[kk][mi]));
            #pragma unroll
            for (int ni = 0; ni < 4; ++ni)
                bb[kk][ni] = __builtin_bit_cast(bf16x8, *(const ushort8*)(Bs + boff[kk][ni]));
        }

        // stage B1 of step k+1 (slot was B1(k-1): reads done last step)
        if (k + 1 < STEPS) { STAGE_B(k + 1, 1, (4 * k + 7) & 7) }

        // all this step's slot-reads must land before slots 4k..4k+2 rewritten
        asm volatile("s_waitcnt lgkmcnt(0)" ::: "memory");
        __builtin_amdgcn_s_barrier();

        __builtin_amdgcn_s_setprio(1);
        if (k + 2 < STEPS) { STAGE_A(k + 2, 0, (4 * k + 8) & 7) }
        #pragma unroll
        for (int ni = 0; ni < 2; ++ni)
            #pragma unroll
            for (int mi = 0; mi < 8; ++mi)
                acc[mi][ni] = __builtin_amdgcn_mfma_f32_16x16x32_bf16(
                    a[0][mi], bb[0][ni], acc[mi][ni], 0, 0, 0);
        if (k + 2 < STEPS) { STAGE_A(k + 2, 1, (4 * k + 9) & 7) }
        #pragma unroll
        for (int ni = 2; ni < 4; ++ni)
            #pragma unroll
            for (int mi = 0; mi < 8; ++mi)
                acc[mi][ni] = __builtin_amdgcn_mfma_f32_16x16x32_bf16(
                    a[0][mi], bb[0][ni], acc[mi][ni], 0, 0, 0);
        if (k + 2 < STEPS) { STAGE_B(k + 2, 0, (4 * k + 10) & 7) }
        #pragma unroll
        for (int ni = 0; ni < 4; ++ni)
            #pragma unroll
            for (int mi = 0; mi < 8; ++mi)
                acc[mi][ni] = __builtin_amdgcn_mfma_f32_16x16x32_bf16(
                    a[1][mi], bb[1][ni], acc[mi][ni], 0, 0, 0);
        __builtin_amdgcn_s_setprio(0);
    }
#undef STAGE_A
#undef STAGE_B

    // ---- epilogue: bias + fp32 store (lp lanes = consecutive px) ----
    #pragma unroll
    for (int ni = 0; ni < 4; ++ni) {
        int px = pix0 + wc * 64 + ni * 16 + lp;
        int n  = px / HW_;
        int pr = px - n * HW_;
        float* ob = out + (size_t)n * K_ * HW_ + pr;
        #pragma unroll
        for (int mi = 0; mi < 8; ++mi) {
            int kb = wr * 128 + mi * 16 + lk * 4;
            f32x4 bv = *(const f32x4*)(bias + kb);
            #pragma unroll
            for (int j = 0; j < 4; ++j)
                ob[(size_t)(kb + j) * HW_] = acc[mi][ni][j] + bv[j];
        }
    }
}

// ---------------- fallback (reg-staged fp32 path, no workspace xp) ---------
__launch_bounds__(256, 2)
__global__ void conv_mfma3_kernel(const float* __restrict__ x,
                                  const unsigned short* __restrict__ wp2,
                                  const float* __restrict__ bias,
                                  float* __restrict__ out) {
    __shared__ unsigned short Xt[2][232 * 40];
    const int t    = threadIdx.x;
    const int lane = t & 63;
    const int wid  = t >> 6;
    const int b    = blockIdx.x;
    const int orig = (b & 7) * 112 + (b >> 3);
    const int n    = orig / 28;
    const int rp   = orig - n * 28;
    const int h0   = rp * 2;
    const int lp = lane & 15;
    const int lk = lane >> 4;
    int bofs[7];
    #pragma unroll
    for (int ni = 0; ni < 7; ++ni) {
        int p  = ni * 16 + lp;
        int hr = (p >= 56) ? 1 : 0;
        int pw = p - hr * 56;
        bofs[ni] = (hr * 58 + pw) * 40 + lk * 8;
    }
    bool  ok[4], v928[4];
    const float* xq[4];
    int   ldsw[4];
    #pragma unroll
    for (int i = 0; i < 4; ++i) {
        int it = i * 256 + t;
        v928[i] = (it < 928);
        int itc  = v928[i] ? it : 0;
        int csub = (itc >= 232) + (itc >= 464) + (itc >= 696);
        int col  = itc - 232 * csub;
        int hh   = col / 58;
        int ww   = col - 58 * hh;
        int hin  = h0 + hh - 1;
        int win  = ww - 1;
        ok[i]   = v928[i] && (unsigned)hin < 56u && (unsigned)win < 56u;
        xq[i]   = x + (((n * C_ + csub * 8) * H_ + hin) * W_ + win);
        ldsw[i] = col * 40 + csub * 8;
    }
    float xv[4][8];
#define STAGE_LOAD(CH)                                                 \
    _Pragma("unroll")                                                  \
    for (int i = 0; i < 4; ++i)                                        \
        _Pragma("unroll")                                              \
        for (int j = 0; j < 8; ++j)                                    \
            xv[i][j] = ok[i] ? xq[i][((CH) * 32 + j) * HW_] : 0.f;
#define STAGE_WRITE(BUF)                                               \
    _Pragma("unroll")                                                  \
    for (int i = 0; i < 4; ++i)                                        \
        if (v928[i]) {                                                 \
            ushort8 v;                                                 \
            _Pragma("unroll")                                          \
            for (int j = 0; j < 8; ++j) v[j] = f2bf(xv[i][j]);         \
            *(ushort8*)(&Xt[BUF][ldsw[i]]) = v;                        \
        }
    f32x4 acc[4][7];
    #pragma unroll
    for (int mi = 0; mi < 4; ++mi)
        #pragma unroll
        for (int ni = 0; ni < 7; ++ni)
            acc[mi][ni] = (f32x4){0.f, 0.f, 0.f, 0.f};
    STAGE_LOAD(0)
    STAGE_WRITE(0)
    __syncthreads();
    const ushort8* W8 = (const ushort8*)wp2;
    for (int cc = 0; cc < 4; ++cc) {
        const int cur = cc & 1;
        if (cc < 3) { STAGE_LOAD(cc + 1) }
        const int tb = wid * 1024 + cc * 64 + lane;
        #pragma unroll
        for (int tap = 0; tap < 9; ++tap) {
            const int r    = tap / 3;
            const int s    = tap - 3 * r;
            const int toff = (r * 58 + s) * 40;
            bf16x8 a[4];
            #pragma unroll
            for (int mi = 0; mi < 4; ++mi)
                a[mi] = __builtin_bit_cast(bf16x8, W8[tap * 4096 + tb + mi * 256]);
            bf16x8 bfr[7];
            #pragma unroll
            for (int ni = 0; ni < 7; ++ni)
                bfr[ni] = __builtin_bit_cast(bf16x8,
                    *(const ushort8*)(&Xt[cur][bofs[ni] + toff]));
            #pragma unroll
            for (int ni = 0; ni < 7; ++ni)
                #pragma unroll
                for (int mi = 0; mi < 4; ++mi)
                    acc[mi][ni] = __builtin_amdgcn_mfma_f32_16x16x32_bf16(
                        a[mi], bfr[ni], acc[mi][ni], 0, 0, 0);
        }
        if (cc < 3) {
            STAGE_WRITE(cur ^ 1)
            __syncthreads();
        }
    }
    #pragma unroll
    for (int mi = 0; mi < 4; ++mi) {
        #pragma unroll
        for (int j = 0; j < 4; ++j) {
            int kout = wid * 64 + mi * 16 + lk * 4 + j;
            float bv = bias[kout];
            float* op = out + ((n * K_ + kout) * H_ + h0) * W_;
            #pragma unroll
            for (int ni = 0; ni < 7; ++ni) {
                int p  = ni * 16 + lp;
                int hr = (p >= 56) ? 1 : 0;
                int pw = p - hr * 56;
                op[hr * W_ + pw] = acc[mi][ni][j] + bv;
            }
        }
    }
#undef STAGE_LOAD
#undef STAGE_WRITE
}

// legacy repack for the fallback path
__global__ void repack_w2_kernel(const float* __restrict__ w,
                                 unsigned short* __restrict__ wp2) {
    int o = blockIdx.x * 256 + threadIdx.x;
    if (o >= 9 * 16 * 4 * 64 * 8) return;
    int j   = o & 7;
    int l   = (o >> 3) & 63;
    int cc  = (o >> 9) & 3;
    int kg  = (o >> 11) & 15;
    int tap = o >> 15;
    int k = kg * 16 + (l & 15);
    int c = cc * 32 + (l >> 4) * 8 + j;
    wp2[o] = f2bf(w[(k * C_ + c) * 9 + tap]);
}

__global__ void conv_naive_kernel(const float* __restrict__ x,
                                  const float* __restrict__ w,
                                  const float* __restrict__ b,
                                  float* __restrict__ out) {
    int idx = blockIdx.x * 256 + threadIdx.x;
    if (idx >= N_ * K_ * HW_) return;
    int pw = idx % 56; int tmp = idx / 56;
    int h  = tmp % 56; tmp /= 56;
    int k  = tmp % 256; int n = tmp / 256;
    float acc = b[k];
    for (int c = 0; c < C_; ++c)
        for (int r = 0; r < 3; ++r) {
            int hin = h + r - 1;
            if ((unsigned)hin >= 56u) continue;
            for (int s = 0; s < 3; ++s) {
                int win = pw + s - 1;
                if ((unsigned)win >= 56u) continue;
                acc += x[((n * C_ + c) * H_ + hin) * W_ + win] * w[(k * C_ + c) * 9 + r * 3 + s];
            }
        }
    out[idx] = acc;
}

extern "C" void kernel_launch(void* const* d_in, const int* in_sizes, int n_in,
                              void* d_out, int out_size, void* d_ws, size_t ws_size,
                              hipStream_t stream) {
    const float* x = (const float*)d_in[0];
    const float* w = (const float*)d_in[1];
    const float* b = (const float*)d_in[2];
    float* out = (float*)d_out;

    const size_t xp_bytes = (size_t)N_ * HP_ * HP_ * C_ * 2;              // 27,557,888
    const size_t wp_bytes = (size_t)STEPS * 2 * 8192 * 2;                 // 589,824

    if (ws_size >= xp_bytes + wp_bytes) {
        unsigned short* xpad = (unsigned short*)d_ws;
        unsigned short* wp4  = (unsigned short*)((char*)d_ws + xp_bytes);
        pack_x_kernel<<<N_ * HP_, 256, 0, stream>>>(x, xpad);
        repack_w4_kernel<<<(STEPS * 2 * 8192 + 255) / 256, 256, 0, stream>>>(w, wp4);
        conv_mfma9_kernel<<<392, 512, 0, stream>>>(xpad, wp4, b, out);
    } else if (ws_size >= wp_bytes) {
        unsigned short* wp2 = (unsigned short*)d_ws;
        repack_w2_kernel<<<(9 * 16 * 4 * 64 * 8 + 255) / 256, 256, 0, stream>>>(w, wp2);
        conv_mfma3_kernel<<<896, 256, 0, stream>>>(x, wp2, b, out);
    } else {
        conv_naive_kernel<<<(N_ * K_ * HW_ + 255) / 256, 256, 0, stream>>>(x, w, b, out);
    }
}